// Round 14
// baseline (49.799 us; speedup 1.0000x reference)
//
#include <hip/hip_runtime.h>

#define NROWS 8192
#define DIM   256          // elements per row == bytes per row in fp8
#define BHALF 4096
#define NCHUNK 8           // col chunks per 128-row panel (1024 cols each)
#define SCALE 1.69864358f  // sqrt(2 * log2(e)): dot = sim * log2(e)
#define LN2F  0.69314718f

typedef unsigned char u8;
typedef __attribute__((ext_vector_type(4))) float f32x4;
typedef __attribute__((ext_vector_type(4))) int   i32x4;
typedef __attribute__((ext_vector_type(8))) int   i32x8;

// exact OCP e4m3fn -> f32 (values here never reach NaN/448)
__device__ inline float fp8_to_f32(int b) {
  const int e = (b >> 3) & 15, m = b & 7;
  float mag = e ? __builtin_bit_cast(float, ((e + 120) << 23) | (m << 20))
                : (float)m * 0x1p-9f;
  return (b & 128) ? -mag : mag;
}

// Kernel 1: row-PAIR normalize (rows r and r+B together): quantize to fp8
// (scaled by sqrt(2*log2e) so Gram dot = sim*log2e), and precompute from the
// DEQUANTIZED values pos[r] (positive-pair dot, nats) and diag[r] (self-dot,
// log2 units). Zeroes rowsum / cnt / out (stream-ordered before sim).
__global__ __launch_bounds__(256) void nrm_kernel(const float* __restrict__ zi,
                                                  const float* __restrict__ zj,
                                                  u8* __restrict__ zn8,
                                                  float* __restrict__ rowsum,
                                                  float* __restrict__ pos,
                                                  float* __restrict__ diag,
                                                  int* __restrict__ cnt,
                                                  float* __restrict__ out) {
  const int t = threadIdx.x, b = blockIdx.x;
  const int gid = b * 256 + t;
  if (gid < NROWS) rowsum[gid] = 0.f;
  if (gid < 64) cnt[gid] = 0;
  if (gid == 0) out[0] = 0.f;

  const int w = t >> 6, l = t & 63;
#pragma unroll
  for (int q = 0; q < 2; ++q) {
    const int p = b * 8 + w * 2 + q;           // pair index 0..4095
    float4 vi = *(const float4*)(zi + (size_t)p * DIM + l * 4);
    float4 vj = *(const float4*)(zj + (size_t)p * DIM + l * 4);
    float ssi = vi.x * vi.x + vi.y * vi.y + vi.z * vi.z + vi.w * vi.w;
    float ssj = vj.x * vj.x + vj.y * vj.y + vj.z * vj.z + vj.w * vj.w;
#pragma unroll
    for (int m = 1; m < 64; m <<= 1) {
      ssi += __shfl_xor(ssi, m);
      ssj += __shfl_xor(ssj, m);
    }
    const float invi = SCALE / fmaxf(sqrtf(ssi), 1e-8f);
    const float invj = SCALE / fmaxf(sqrtf(ssj), 1e-8f);
    int pi = __builtin_amdgcn_cvt_pk_fp8_f32(vi.x * invi, vi.y * invi, 0, false);
    pi = __builtin_amdgcn_cvt_pk_fp8_f32(vi.z * invi, vi.w * invi, pi, true);
    int pj = __builtin_amdgcn_cvt_pk_fp8_f32(vj.x * invj, vj.y * invj, 0, false);
    pj = __builtin_amdgcn_cvt_pk_fp8_f32(vj.z * invj, vj.w * invj, pj, true);
    *(int*)(zn8 + (size_t)p * DIM + l * 4) = pi;
    *(int*)(zn8 + (size_t)(p + BHALF) * DIM + l * 4) = pj;

    // dequantized dot / self-dots (match MFMA values to summation rounding)
    float dot = 0.f, di = 0.f, dj = 0.f;
#pragma unroll
    for (int k2 = 0; k2 < 4; ++k2) {
      const float qi = fp8_to_f32((pi >> (8 * k2)) & 255);
      const float qj = fp8_to_f32((pj >> (8 * k2)) & 255);
      dot += qi * qj; di += qi * qi; dj += qj * qj;
    }
#pragma unroll
    for (int m = 1; m < 64; m <<= 1) {
      dot += __shfl_xor(dot, m);
      di  += __shfl_xor(di, m);
      dj  += __shfl_xor(dj, m);
    }
    if      (l == 0) pos[p] = dot * LN2F;            // nats
    else if (l == 1) pos[p + BHALF] = dot * LN2F;
    else if (l == 2) diag[p] = di;                   // log2 units
    else if (l == 3) diag[p + BHALF] = dj;
  }
}

// Kernel 2: BARRIER-FREE full-matrix row-sum sweep. Everything direct from
// L2 (zn8 = 2MB, resident per XCD): panel fragments pb loaded to registers
// in the prologue; streamed A-fragments flow through a 4-slot register FIFO
// (slot = ci, static) with distance-4 prefetch -- refill issued before the
// exp2 burst, pinned by sched_barrier. NO LDS staging, NO s_barrier, NO
// vmcnt(0) drains in the loop: each wave self-paces on compiler-counted
// vmcnt, so the 8 waves/CU drift and their MFMA/VALU/trans phases interleave
// (the per-tile lockstep stall was the measured ~2800cyc/tile residual).
__global__ __launch_bounds__(256, 2) void sim_kernel(const u8* __restrict__ zn8,
                                                     float* __restrict__ rowsum,
                                                     const float* __restrict__ pos,
                                                     const float* __restrict__ diag,
                                                     int* __restrict__ cnt,
                                                     float* __restrict__ out) {
  __shared__ float plane[2][128];
  __shared__ float wsum[2];
  __shared__ int sfin;

  const int t = threadIdx.x;
  const int w = t >> 6, l = t & 63;
  const int wa = w >> 1, wb = w & 1;    // wa: col 64-half, wb: panel-row 64-half
  const int rl = l & 15, kg = l >> 4;   // kg = lane's 32B sub-block per k-half

  const int rp = (int)blockIdx.x >> 3;  // row panel 0..63
  const int ch = (int)blockIdx.x & 7;   // col chunk 0..7
  const int colbase = ch * 1024;        // zn8 row index of first streamed tile

  // direct L2 fragment fetch: 32B at k=0 half + 32B at k=1 half of `row`.
  // per-instruction pattern: 16 consecutive rows x full 128B k-half (kg
  // spreads 4x32B) -> line-complete L2 requests.
  auto GRD = [&](int row, i32x4* s) {
    const u8* base = zn8 + (size_t)row * DIM + kg * 32;
    s[0] = *(const i32x4*)(base);
    s[1] = *(const i32x4*)(base + 16);
    s[2] = *(const i32x4*)(base + 128);
    s[3] = *(const i32x4*)(base + 144);
  };

  // panel fragments (B-operand) straight to registers
  i32x4 pt[4][4];
#pragma unroll
  for (int pj = 0; pj < 4; ++pj)
    GRD(rp * 128 + wb * 64 + pj * 16 + rl, pt[pj]);
  // streamed A FIFO: fill all 4 slots with tile 0
  i32x4 af[4][4];
#pragma unroll
  for (int ci = 0; ci < 4; ++ci)
    GRD(colbase + wa * 64 + ci * 16 + rl, af[ci]);
  __builtin_amdgcn_sched_barrier(0);    // pin prologue issues

  i32x8 pb[4][2];
#pragma unroll
  for (int pj = 0; pj < 4; ++pj) {
    pb[pj][0] = __builtin_shufflevector(pt[pj][0], pt[pj][1], 0, 1, 2, 3, 4, 5, 6, 7);
    pb[pj][1] = __builtin_shufflevector(pt[pj][2], pt[pj][3], 0, 1, 2, 3, 4, 5, 6, 7);
  }

  float rsum[4] = {0.f, 0.f, 0.f, 0.f};
  const f32x4 z4 = {0.f, 0.f, 0.f, 0.f};

#pragma unroll 2
  for (int ti = 0; ti < 8; ++ti) {
    const int tn = (ti < 7) ? ti + 1 : 7;            // tail re-reads tile 7
    const int nbase = colbase + tn * 128 + wa * 64 + rl;

#pragma unroll
    for (int ci = 0; ci < 4; ++ci) {
      // consume slot ci (loaded one tile ago; compiler emits counted vmcnt)
      i32x8 a0 = __builtin_shufflevector(af[ci][0], af[ci][1], 0, 1, 2, 3, 4, 5, 6, 7);
      i32x8 a1 = __builtin_shufflevector(af[ci][2], af[ci][3], 0, 1, 2, 3, 4, 5, 6, 7);
      f32x4 acc[4];
      __builtin_amdgcn_s_setprio(1);
#pragma unroll
      for (int pj = 0; pj < 4; ++pj)    // k=0: C = literal zero
        acc[pj] = __builtin_amdgcn_mfma_scale_f32_16x16x128_f8f6f4(
            a0, pb[pj][0], z4, 0, 0, 0, 0x7f7f7f7f, 0, 0x7f7f7f7f);
#pragma unroll
      for (int pj = 0; pj < 4; ++pj)    // k=1: accumulate
        acc[pj] = __builtin_amdgcn_mfma_scale_f32_16x16x128_f8f6f4(
            a1, pb[pj][1], acc[pj], 0, 0, 0, 0x7f7f7f7f, 0, 0x7f7f7f7f);
      __builtin_amdgcn_s_setprio(0);

      // refill slot ci from the next tile -- issued BEFORE the exp2 burst
      GRD(nbase + ci * 16, af[ci]);
      __builtin_amdgcn_sched_barrier(0);  // loads may not sink below here

      // epilogue: exp2 + lane-local row-sum
#pragma unroll
      for (int pj = 0; pj < 4; ++pj)
#pragma unroll
        for (int jj = 0; jj < 4; ++jj)
          rsum[pj] += __builtin_amdgcn_exp2f(acc[pj][jj]);
    }
  }

  // reduce rsum over the 4 kg lane-groups (bits 4..5), once per block
#pragma unroll
  for (int pj = 0; pj < 4; ++pj) {
    rsum[pj] += __shfl_xor(rsum[pj], 16);
    rsum[pj] += __shfl_xor(rsum[pj], 32);
  }
  if (kg == 0) {
#pragma unroll
    for (int pj = 0; pj < 4; ++pj)
      plane[wa][wb * 64 + pj * 16 + rl] = rsum[pj];
  }
  __syncthreads();

  // ---- fence-free fused finish ----
  if (t < 128)
    atomicAdd(&rowsum[rp * 128 + t], plane[0][t] + plane[1][t]);
  asm volatile("s_waitcnt vmcnt(0)" ::: "memory");   // my atomics at coherence
  __syncthreads();
  if (t == 0) sfin = (atomicAdd(&cnt[rp], 1) == NCHUNK - 1);
  __syncthreads();
  if (sfin) {                           // 8th arrival: all panels' adds landed
    float v = 0.f;
    if (t < 128) {
      const int r = rp * 128 + t;
      float s = atomicAdd(&rowsum[r], 0.f);          // coherent read
      v = logf(s - __builtin_amdgcn_exp2f(diag[r])) - pos[r];
    }
#pragma unroll
    for (int m = 1; m < 64; m <<= 1) v += __shfl_xor(v, m);
    if (l == 0 && t < 128) wsum[w] = v;
    __syncthreads();
    if (t == 0) atomicAdd(out, (wsum[0] + wsum[1]) * (1.f / NROWS));
  }
}

extern "C" void kernel_launch(void* const* d_in, const int* in_sizes, int n_in,
                              void* d_out, int out_size, void* d_ws, size_t ws_size,
                              hipStream_t stream) {
  const float* zi = (const float*)d_in[0];
  const float* zj = (const float*)d_in[1];

  u8*    zn8    = (u8*)d_ws;                                        // 2 MB
  float* rowsum = (float*)((char*)d_ws + (size_t)NROWS * DIM);      // 32 KB
  float* pos    = (float*)((char*)rowsum + (size_t)NROWS * 4);      // 32 KB
  float* diag   = (float*)((char*)pos + (size_t)NROWS * 4);         // 32 KB
  int*   cnt    = (int*)((char*)diag + (size_t)NROWS * 4);          // 256 B
  float* out    = (float*)d_out;

  nrm_kernel<<<512, 256, 0, stream>>>(zi, zj, zn8, rowsum, pos, diag, cnt, out);
  sim_kernel<<<64 * NCHUNK, 256, 0, stream>>>(zn8, rowsum, pos, diag, cnt, out);
}